// Round 1
// baseline (270.068 us; speedup 1.0000x reference)
//
#include <hip/hip_runtime.h>
#include <hip/hip_bf16.h>

// HelicalAttention on MI355X (gfx950).
// B=2,S=2048,E=1024,H=16,HD=64,HX=64,P=32. All heavy math in bf16 MFMA
// (16x16x32), fp32 accumulate. Score = (q/16)·k + (qs/8)·(ks/8) folded into
// one K=128 contraction (power-of-2 scales are exact in bf16).
// Flash-style attention with NO max subtraction (scores bounded ~|2.5|).

typedef unsigned short u16;
typedef unsigned int u32;
typedef __attribute__((ext_vector_type(8))) __bf16 bf16x8;
typedef __attribute__((ext_vector_type(4))) float f32x4;

__device__ __forceinline__ u16 f2b(float f) {
  u32 u = __float_as_uint(f);
  u32 r = (u + 0x7fffu + ((u >> 16) & 1u)) >> 16;
  return (u16)r;
}
__device__ __forceinline__ float b2f(u16 h) {
  return __uint_as_float(((u32)h) << 16);
}

__device__ __forceinline__ f32x4 mfma16(bf16x8 a, bf16x8 b, f32x4 c) {
  return __builtin_amdgcn_mfma_f32_16x16x32_bf16(a, b, c, 0, 0, 0);
}

// async global->LDS, 16B per lane. LDS dest must be wave-uniform-base + lane*16.
__device__ __forceinline__ void gld16(void* lds, const void* g) {
  __builtin_amdgcn_global_load_lds(
      (const __attribute__((address_space(1))) unsigned int*)g,
      (__attribute__((address_space(3))) unsigned int*)lds, 16, 0, 0);
}

// ---------------------------------------------------------------- cast -----
// x (4194304 f32) -> xb ; Wq|Wk|Wv -> wb (contiguous, 1048576 each) ;
// Wo -> wob ; Whel -> whb.  Processed in float4 quads; region boundaries are
// multiples of 256 quads so blocks never straddle regions.
__global__ __launch_bounds__(256) void cast_kernel(
    const float* __restrict__ x,  const float* __restrict__ wq,
    const float* __restrict__ wk, const float* __restrict__ wv,
    const float* __restrict__ wo, const float* __restrict__ whel,
    u16* __restrict__ xb, u16* __restrict__ wb, u16* __restrict__ wob,
    u16* __restrict__ whb) {
  long long q = (long long)blockIdx.x * 256 + threadIdx.x;
  const float* s; u16* d; long long base;
  if (q < 1048576)      { s = x;    d = xb;            base = 0; }
  else if (q < 1310720) { s = wq;   d = wb;            base = 1048576; }
  else if (q < 1572864) { s = wk;   d = wb + 1048576;  base = 1310720; }
  else if (q < 1835008) { s = wv;   d = wb + 2097152;  base = 1572864; }
  else if (q < 2097152) { s = wo;   d = wob;           base = 1835008; }
  else                  { s = whel; d = whb;           base = 2097152; }
  long long e = (q - base) * 4;
  float4 v = *(const float4*)(s + e);
  ushort4 o;
  o.x = f2b(v.x); o.y = f2b(v.y); o.z = f2b(v.z); o.w = f2b(v.w);
  *(ushort4*)(d + e) = o;
}

// ------------------------------------------------------------ QKV GEMM -----
// C[m,n] = sum_k xb[m,k]*W[n,k] + bias[n].  m97 structure: 128x128 tile,
// BK=32, 4 waves in 2x2, each 64x64 via 4x4 of 16x16x32 MFMA.
// which=0 -> Qcat[bh][s][0:64] = q/16 ; which=1 -> Kcat[bh][s][0:64] = k ;
// which=2 -> vT[bh][d][t] = v (pre-transposed for attention B-operand).
__global__ __launch_bounds__(256, 2) void qkv_gemm(
    const u16* __restrict__ xb, const u16* __restrict__ wb,
    const float* __restrict__ bq, const float* __restrict__ bk,
    const float* __restrict__ bv,
    u16* __restrict__ Qcat, u16* __restrict__ Kcat, u16* __restrict__ vt) {
  __shared__ u16 Al[128][32];
  __shared__ u16 Bl[128][32];
  const int nt = blockIdx.x, mt = blockIdx.y;
  const int which = nt >> 3;
  const int n0 = (nt & 7) << 7;
  const int m0 = mt << 7;
  const int tid = threadIdx.x;
  const int wave = tid >> 6, lane = tid & 63;
  const int g = lane >> 4, c15 = lane & 15;
  const int wm = wave & 1, wn = wave >> 1;
  const u16* Wp = wb + (long long)which * (1024 * 1024) + n0 * 1024;
  const u16* Ap = xb + m0 * 1024;
  const int srow = (wave * 64 + lane) >> 2;  // 0..63
  const int scol = (lane & 3) << 3;          // 0,8,16,24

  f32x4 acc[4][4];
#pragma unroll
  for (int i = 0; i < 4; i++)
#pragma unroll
    for (int j = 0; j < 4; j++) acc[i][j] = f32x4{0.f, 0.f, 0.f, 0.f};

  for (int k0 = 0; k0 < 1024; k0 += 32) {
    gld16(&Al[srow][scol],      Ap + srow * 1024 + k0 + scol);
    gld16(&Al[64 + srow][scol], Ap + (64 + srow) * 1024 + k0 + scol);
    gld16(&Bl[srow][scol],      Wp + srow * 1024 + k0 + scol);
    gld16(&Bl[64 + srow][scol], Wp + (64 + srow) * 1024 + k0 + scol);
    __syncthreads();
    bf16x8 a[4], b[4];
#pragma unroll
    for (int i = 0; i < 4; i++)
      a[i] = *(const bf16x8*)&Al[wm * 64 + i * 16 + c15][g * 8];
#pragma unroll
    for (int j = 0; j < 4; j++)
      b[j] = *(const bf16x8*)&Bl[wn * 64 + j * 16 + c15][g * 8];
#pragma unroll
    for (int i = 0; i < 4; i++)
#pragma unroll
      for (int j = 0; j < 4; j++) acc[i][j] = mfma16(a[i], b[j], acc[i][j]);
    __syncthreads();
  }

  const float* bias = (which == 0) ? bq : ((which == 1) ? bk : bv);
#pragma unroll
  for (int i = 0; i < 4; i++)
#pragma unroll
    for (int j = 0; j < 4; j++)
#pragma unroll
      for (int r = 0; r < 4; r++) {
        int row = m0 + wm * 64 + i * 16 + g * 4 + r;  // token 0..4095
        int col = n0 + wn * 64 + j * 16 + c15;        // 0..1023
        float v = acc[i][j][r] + bias[col];
        int bb = row >> 11, s = row & 2047;
        int hh = col >> 6, d = col & 63;
        if (which == 0) {
          Qcat[(((bb * 16 + hh) * 2048) + s) * 128 + d] = f2b(v * 0.0625f);
        } else if (which == 1) {
          Kcat[(((bb * 16 + hh) * 2048) + s) * 128 + d] = f2b(v);
        } else {
          vt[((bb * 16 + hh) * 64 + d) * 2048 + s] = f2b(v);
        }
      }
}

// ------------------------------------------------------------- helical -----
// Per (bh, 64-row s-block): hel = rows(64x64) @ Whel[h]^T (64x64) + bhel,
// normalize 2D pairs, apply scramble, write /8 into Qcat/Kcat cols [64:128).
// Scramble: orig row s, pair p, coord c -> dest row (c?1024:0)+(s>>1),
// dest col 64 + 2p + (s&1).
__global__ __launch_bounds__(256, 2) void helical_kernel(
    u16* __restrict__ Qcat, u16* __restrict__ Kcat,
    const u16* __restrict__ whb, const float* __restrict__ bhel) {
  __shared__ u16 A[2][2][64][32];  // [q/k][kq][row][32]
  __shared__ u16 Wl[2][64][32];    // Whel[h] bf16, [kq][e][32]
  const int sb = blockIdx.x, bh = blockIdx.y;
  const int h = bh & 15;
  const int s0 = sb << 6;
  const int tid = threadIdx.x;
  const int wave = tid >> 6, lane = tid & 63;
  const int g = lane >> 4, c15 = lane & 15;
  u16* Qb = Qcat + (long long)bh * (2048 * 128);
  u16* Kb = Kcat + (long long)bh * (2048 * 128);

#pragma unroll
  for (int it = 0; it < 2; ++it) {  // stage Whel[h]
    int cidx = it * 256 + tid;
    int e = cidx >> 3, ds = (cidx & 7) << 3;
    uint4 vv = *(const uint4*)(whb + h * 4096 + e * 64 + ds);
    *(uint4*)&Wl[ds >> 5][e][ds & 31] = vv;
  }
#pragma unroll
  for (int it = 0; it < 4; ++it) {  // stage q (x16 to undo /16) and k rows
    int cidx = it * 256 + tid;
    int which = cidx >> 9;
    int r = (cidx >> 3) & 63;
    int ds = (cidx & 7) << 3;
    const u16* src = (which ? Kb : Qb) + (s0 + r) * 128 + ds;
    uint4 vv = *(const uint4*)src;
    if (which == 0) {
      u16 tmp[8];
      *(uint4*)tmp = vv;
#pragma unroll
      for (int q = 0; q < 8; ++q) tmp[q] = f2b(b2f(tmp[q]) * 16.0f);  // exact
      vv = *(uint4*)tmp;
    }
    *(uint4*)&A[which][ds >> 5][r][ds & 31] = vv;
  }
  __syncthreads();

  const int which = wave >> 1, hf = wave & 1;
  f32x4 acc[2][4];
#pragma unroll
  for (int i = 0; i < 2; i++)
#pragma unroll
    for (int j = 0; j < 4; j++) acc[i][j] = f32x4{0.f, 0.f, 0.f, 0.f};
#pragma unroll
  for (int kq = 0; kq < 2; ++kq) {
    bf16x8 a0 = *(const bf16x8*)&A[which][kq][hf * 32 + c15][g * 8];
    bf16x8 a1 = *(const bf16x8*)&A[which][kq][hf * 32 + 16 + c15][g * 8];
#pragma unroll
    for (int j = 0; j < 4; ++j) {
      bf16x8 bb = *(const bf16x8*)&Wl[kq][j * 16 + c15][g * 8];
      acc[0][j] = mfma16(a0, bb, acc[0][j]);
      acc[1][j] = mfma16(a1, bb, acc[1][j]);
    }
  }
  u16* Dst = which ? Kb : Qb;
#pragma unroll
  for (int i = 0; i < 2; ++i)
#pragma unroll
    for (int j = 0; j < 4; ++j)
#pragma unroll
      for (int r = 0; r < 4; ++r) {
        int s_loc = hf * 32 + i * 16 + g * 4 + r;
        int e = j * 16 + c15;
        float v = acc[i][j][r] + bhel[h * 64 + e];
        float pp = __shfl_xor(v, 1);  // pair partner (e^1), same row
        float nn = sqrtf(v * v + pp * pp);
        float o = v / fmaxf(nn, 1e-12f) * 0.125f;  // /8 (exact pow2)
        int s = s0 + s_loc;
        int u = s >> 1, c2 = s & 1;
        int row_out = ((e & 1) ? 1024 : 0) + u;
        int col_out = 64 + (e & ~1) + c2;
        Dst[row_out * 128 + col_out] = f2b(o);
      }
}

// ----------------------------------------------------------- attention -----
// Per (bh, 128-row Q-tile): Q fragments held in REGISTERS (32 VGPR), loop
// over 32 K-tiles of 64: scores via K=128 MFMA, exp (no max needed),
// P->LDS bf16, PV MFMA with pre-transposed V. num/den accumulate, divide at
// the end. LDS = 16+8+16 = 40 KB -> >=3 blocks/CU.
__global__ __launch_bounds__(256, 2) void attn_kernel(
    const u16* __restrict__ Qcat, const u16* __restrict__ Kcat,
    const u16* __restrict__ vt, u16* __restrict__ AO) {
  __shared__ u16 Kl[4][64][32];   // [kq][t-row][32]
  __shared__ u16 Vl[2][64][32];   // [tq][d-row][32 t]
  __shared__ u16 Pl[2][128][32];  // [tq][m-row][32 t]
  const int qt = blockIdx.x, bh = blockIdx.y;
  const int bb = bh >> 4, h = bh & 15;
  const int q0 = qt << 7;
  const int tid = threadIdx.x;
  const int wave = tid >> 6, lane = tid & 63;
  const int g = lane >> 4, c15 = lane & 15;
  const u16* Qb = Qcat + (long long)bh * (2048 * 128);
  const u16* Kb = Kcat + (long long)bh * (2048 * 128);
  const u16* Vb = vt + (long long)bh * (64 * 2048);
  const int r4 = (wave * 64 + lane) >> 2;
  const int c8 = (lane & 3) << 3;
  const int lin8 = (wave * 64 + lane) * 8;

  // Q fragments direct from global (one-time, 8 x 16B per lane)
  bf16x8 qf[2][4];
#pragma unroll
  for (int i = 0; i < 2; ++i)
#pragma unroll
    for (int kq = 0; kq < 4; ++kq)
      qf[i][kq] = *(const bf16x8*)(Qb + (q0 + wave * 32 + i * 16 + c15) * 128 +
                                   kq * 32 + g * 8);

  f32x4 accO[2][4];
  float den[2][4];
#pragma unroll
  for (int i = 0; i < 2; i++)
#pragma unroll
    for (int j = 0; j < 4; j++) accO[i][j] = f32x4{0.f, 0.f, 0.f, 0.f};
#pragma unroll
  for (int i = 0; i < 2; i++)
#pragma unroll
    for (int r = 0; r < 4; r++) den[i][r] = 0.f;

  for (int t = 0; t < 32; ++t) {
    const int t0 = t << 6;
#pragma unroll
    for (int kq = 0; kq < 4; ++kq)
      gld16(((u16*)Kl) + kq * 2048 + lin8, Kb + (t0 + r4) * 128 + kq * 32 + c8);
#pragma unroll
    for (int tq = 0; tq < 2; ++tq)
      gld16(((u16*)Vl) + tq * 2048 + lin8, Vb + r4 * 2048 + t0 + tq * 32 + c8);
    __syncthreads();

    // scores: D[m][t'] = sum_128 Qcat*Kcat  (scales pre-folded)
    f32x4 accS[2][4];
#pragma unroll
    for (int i = 0; i < 2; i++)
#pragma unroll
      for (int j = 0; j < 4; j++) accS[i][j] = f32x4{0.f, 0.f, 0.f, 0.f};
#pragma unroll
    for (int kq = 0; kq < 4; ++kq) {
#pragma unroll
      for (int j = 0; j < 4; ++j) {
        bf16x8 bk2 = *(const bf16x8*)&Kl[kq][j * 16 + c15][g * 8];
        accS[0][j] = mfma16(qf[0][kq], bk2, accS[0][j]);
        accS[1][j] = mfma16(qf[1][kq], bk2, accS[1][j]);
      }
    }

    // exp, write P (bf16) to LDS, accumulate row-sum den
#pragma unroll
    for (int i = 0; i < 2; ++i) {
      float rs[4] = {0.f, 0.f, 0.f, 0.f};
#pragma unroll
      for (int j = 0; j < 4; ++j) {
        int tq = j >> 1;
        int tc = ((j & 1) << 4) + c15;
        int mrow = wave * 32 + i * 16 + g * 4;
#pragma unroll
        for (int r = 0; r < 4; ++r) {
          float p = __expf(accS[i][j][r]);
          rs[r] += p;
          Pl[tq][mrow + r][tc] = f2b(p);
        }
      }
#pragma unroll
      for (int r = 0; r < 4; ++r) {
        float v = rs[r];
        v += __shfl_xor(v, 1);
        v += __shfl_xor(v, 2);
        v += __shfl_xor(v, 4);
        v += __shfl_xor(v, 8);
        den[i][r] += v;
      }
    }

    // O += P @ V   (P rows are per-wave private -> no barrier needed)
#pragma unroll
    for (int tq = 0; tq < 2; ++tq) {
      bf16x8 a0 = *(const bf16x8*)&Pl[tq][wave * 32 + c15][g * 8];
      bf16x8 a1 = *(const bf16x8*)&Pl[tq][wave * 32 + 16 + c15][g * 8];
#pragma unroll
      for (int j = 0; j < 4; ++j) {
        bf16x8 bv2 = *(const bf16x8*)&Vl[tq][j * 16 + c15][g * 8];
        accO[0][j] = mfma16(a0, bv2, accO[0][j]);
        accO[1][j] = mfma16(a1, bv2, accO[1][j]);
      }
    }
    __syncthreads();
  }

#pragma unroll
  for (int i = 0; i < 2; ++i)
#pragma unroll
    for (int j = 0; j < 4; ++j)
#pragma unroll
      for (int r = 0; r < 4; ++r) {
        int m = wave * 32 + i * 16 + g * 4 + r;
        int s = q0 + m;
        float o = accO[i][j][r] / den[i][r];
        int d = j * 16 + c15;
        AO[((bb * 2048 + s) * 1024) + h * 64 + d] = f2b(o);
      }
}

// ----------------------------------------------------------- out GEMM -----
// out[m,n] = sum_k AO[m,k]*Wo[n,k] + bo[n]  (fp32 output)
__global__ __launch_bounds__(256, 2) void out_gemm(
    const u16* __restrict__ AO, const u16* __restrict__ wob,
    const float* __restrict__ bo, float* __restrict__ out) {
  __shared__ u16 Al[128][32];
  __shared__ u16 Bl[128][32];
  const int n0 = blockIdx.x << 7;
  const int m0 = blockIdx.y << 7;
  const int tid = threadIdx.x;
  const int wave = tid >> 6, lane = tid & 63;
  const int g = lane >> 4, c15 = lane & 15;
  const int wm = wave & 1, wn = wave >> 1;
  const u16* Wp = wob + n0 * 1024;
  const u16* Ap = AO + m0 * 1024;
  const int srow = (wave * 64 + lane) >> 2;
  const int scol = (lane & 3) << 3;

  f32x4 acc[4][4];
#pragma unroll
  for (int i = 0; i < 4; i++)
#pragma unroll
    for (int j = 0; j < 4; j++) acc[i][j] = f32x4{0.f, 0.f, 0.f, 0.f};

  for (int k0 = 0; k0 < 1024; k0 += 32) {
    gld16(&Al[srow][scol],      Ap + srow * 1024 + k0 + scol);
    gld16(&Al[64 + srow][scol], Ap + (64 + srow) * 1024 + k0 + scol);
    gld16(&Bl[srow][scol],      Wp + srow * 1024 + k0 + scol);
    gld16(&Bl[64 + srow][scol], Wp + (64 + srow) * 1024 + k0 + scol);
    __syncthreads();
    bf16x8 a[4], b[4];
#pragma unroll
    for (int i = 0; i < 4; i++)
      a[i] = *(const bf16x8*)&Al[wm * 64 + i * 16 + c15][g * 8];
#pragma unroll
    for (int j = 0; j < 4; j++)
      b[j] = *(const bf16x8*)&Bl[wn * 64 + j * 16 + c15][g * 8];
#pragma unroll
    for (int i = 0; i < 4; i++)
#pragma unroll
      for (int j = 0; j < 4; j++) acc[i][j] = mfma16(a[i], b[j], acc[i][j]);
    __syncthreads();
  }
#pragma unroll
  for (int i = 0; i < 4; i++)
#pragma unroll
    for (int j = 0; j < 4; j++)
#pragma unroll
      for (int r = 0; r < 4; r++) {
        int row = m0 + wm * 64 + i * 16 + g * 4 + r;
        int col = n0 + wn * 64 + j * 16 + c15;
        out[row * 1024 + col] = acc[i][j][r] + bo[col];
      }
}

// -------------------------------------------------------------- launch -----
extern "C" void kernel_launch(void* const* d_in, const int* in_sizes, int n_in,
                              void* d_out, int out_size, void* d_ws,
                              size_t ws_size, hipStream_t stream) {
  const float* x    = (const float*)d_in[0];
  const float* Wq   = (const float*)d_in[1];
  const float* bq   = (const float*)d_in[2];
  const float* Wk   = (const float*)d_in[3];
  const float* bk   = (const float*)d_in[4];
  const float* Wv   = (const float*)d_in[5];
  const float* bv   = (const float*)d_in[6];
  const float* Wo   = (const float*)d_in[7];
  const float* bo   = (const float*)d_in[8];
  const float* Whel = (const float*)d_in[9];
  const float* bhel = (const float*)d_in[10];
  float* out = (float*)d_out;

  char* ws = (char*)d_ws;
  u16* xb   = (u16*)(ws + 0);                  //  8 MB
  u16* wb   = (u16*)(ws + 8388608);            //  6 MB (Wq|Wk|Wv)
  u16* wob  = (u16*)(ws + 14680064);           //  2 MB
  u16* whb  = (u16*)(ws + 16777216);           //  128 KB
  u16* Qcat = (u16*)(ws + 16908288);           // 16 MB  [bh][s][128]
  u16* Kcat = (u16*)(ws + 33685504);           // 16 MB
  u16* vt   = (u16*)(ws + 50462720);           //  8 MB  [bh][d][t]
  u16* AO   = (u16*)(ws + 58851328);           //  8 MB  (total ~64.1 MB)

  dim3 blk(256);
  cast_kernel<<<dim3(8256), blk, 0, stream>>>(x, Wq, Wk, Wv, Wo, Whel, xb, wb,
                                              wob, whb);
  qkv_gemm<<<dim3(24, 32), blk, 0, stream>>>(xb, wb, bq, bk, bv, Qcat, Kcat,
                                             vt);
  helical_kernel<<<dim3(32, 32), blk, 0, stream>>>(Qcat, Kcat, whb, bhel);
  attn_kernel<<<dim3(16, 32), blk, 0, stream>>>(Qcat, Kcat, vt, AO);
  out_gemm<<<dim3(8, 32), blk, 0, stream>>>(AO, wob, bo, out);
}

// Round 2
// 254.638 us; speedup vs baseline: 1.0606x; 1.0606x over previous
//
#include <hip/hip_runtime.h>
#include <hip/hip_bf16.h>

// HelicalAttention on MI355X (gfx950).
// B=2,S=2048,E=1024,H=16,HD=64,HX=64,P=32. All heavy math in bf16 MFMA
// (16x16x32), fp32 accumulate. Score = (q/16)·k + (qs/8)·(ks/8) folded into
// one K=128 contraction (power-of-2 scales are exact in bf16).
// Flash-style attention with NO max subtraction (scores bounded ~|2.5|).
// R2: attn Q-tile 64 (1024 blocks, 4/CU), deferred den reduction, truncating
// P->bf16, padded Pl (40 u16 rows); qkv V-transpose via LDS (coalesced vt).

typedef unsigned short u16;
typedef unsigned int u32;
typedef __attribute__((ext_vector_type(8))) __bf16 bf16x8;
typedef __attribute__((ext_vector_type(4))) float f32x4;

__device__ __forceinline__ u16 f2b(float f) {
  u32 u = __float_as_uint(f);
  u32 r = (u + 0x7fffu + ((u >> 16) & 1u)) >> 16;
  return (u16)r;
}
__device__ __forceinline__ float b2f(u16 h) {
  return __uint_as_float(((u32)h) << 16);
}

__device__ __forceinline__ f32x4 mfma16(bf16x8 a, bf16x8 b, f32x4 c) {
  return __builtin_amdgcn_mfma_f32_16x16x32_bf16(a, b, c, 0, 0, 0);
}

// async global->LDS, 16B per lane. LDS dest must be wave-uniform-base + lane*16.
__device__ __forceinline__ void gld16(void* lds, const void* g) {
  __builtin_amdgcn_global_load_lds(
      (const __attribute__((address_space(1))) unsigned int*)g,
      (__attribute__((address_space(3))) unsigned int*)lds, 16, 0, 0);
}

// ---------------------------------------------------------------- cast -----
__global__ __launch_bounds__(256) void cast_kernel(
    const float* __restrict__ x,  const float* __restrict__ wq,
    const float* __restrict__ wk, const float* __restrict__ wv,
    const float* __restrict__ wo, const float* __restrict__ whel,
    u16* __restrict__ xb, u16* __restrict__ wb, u16* __restrict__ wob,
    u16* __restrict__ whb) {
  long long q = (long long)blockIdx.x * 256 + threadIdx.x;
  const float* s; u16* d; long long base;
  if (q < 1048576)      { s = x;    d = xb;            base = 0; }
  else if (q < 1310720) { s = wq;   d = wb;            base = 1048576; }
  else if (q < 1572864) { s = wk;   d = wb + 1048576;  base = 1310720; }
  else if (q < 1835008) { s = wv;   d = wb + 2097152;  base = 1572864; }
  else if (q < 2097152) { s = wo;   d = wob;           base = 1835008; }
  else                  { s = whel; d = whb;           base = 2097152; }
  long long e = (q - base) * 4;
  float4 v = *(const float4*)(s + e);
  ushort4 o;
  o.x = f2b(v.x); o.y = f2b(v.y); o.z = f2b(v.z); o.w = f2b(v.w);
  *(ushort4*)(d + e) = o;
}

// ------------------------------------------------------------ QKV GEMM -----
// C[m,n] = sum_k xb[m,k]*W[n,k] + bias[n].  128x128 tile, BK=32, 4 waves.
// which=0 -> Qcat[bh][s][0:64] = q/16 ; which=1 -> Kcat[bh][s][0:64] = k ;
// which=2 -> vT[bh][d][t] = v via LDS transpose (coalesced stores).
__global__ __launch_bounds__(256, 2) void qkv_gemm(
    const u16* __restrict__ xb, const u16* __restrict__ wb,
    const float* __restrict__ bq, const float* __restrict__ bk,
    const float* __restrict__ bv,
    u16* __restrict__ Qcat, u16* __restrict__ Kcat, u16* __restrict__ vt) {
  __shared__ u16 Al[128][32];
  __shared__ u16 Bl[128][32];
  __shared__ u16 T[64][136];  // transpose staging for V (padded, 16B rows)
  const int nt = blockIdx.x, mt = blockIdx.y;
  const int which = nt >> 3;
  const int n0 = (nt & 7) << 7;
  const int m0 = mt << 7;
  const int tid = threadIdx.x;
  const int wave = tid >> 6, lane = tid & 63;
  const int g = lane >> 4, c15 = lane & 15;
  const int wm = wave & 1, wn = wave >> 1;
  const u16* Wp = wb + (long long)which * (1024 * 1024) + n0 * 1024;
  const u16* Ap = xb + m0 * 1024;
  const int srow = (wave * 64 + lane) >> 2;  // 0..63
  const int scol = (lane & 3) << 3;          // 0,8,16,24

  f32x4 acc[4][4];
#pragma unroll
  for (int i = 0; i < 4; i++)
#pragma unroll
    for (int j = 0; j < 4; j++) acc[i][j] = f32x4{0.f, 0.f, 0.f, 0.f};

  for (int k0 = 0; k0 < 1024; k0 += 32) {
    gld16(&Al[srow][scol],      Ap + srow * 1024 + k0 + scol);
    gld16(&Al[64 + srow][scol], Ap + (64 + srow) * 1024 + k0 + scol);
    gld16(&Bl[srow][scol],      Wp + srow * 1024 + k0 + scol);
    gld16(&Bl[64 + srow][scol], Wp + (64 + srow) * 1024 + k0 + scol);
    __syncthreads();
    bf16x8 a[4], b[4];
#pragma unroll
    for (int i = 0; i < 4; i++)
      a[i] = *(const bf16x8*)&Al[wm * 64 + i * 16 + c15][g * 8];
#pragma unroll
    for (int j = 0; j < 4; j++)
      b[j] = *(const bf16x8*)&Bl[wn * 64 + j * 16 + c15][g * 8];
#pragma unroll
    for (int i = 0; i < 4; i++)
#pragma unroll
      for (int j = 0; j < 4; j++) acc[i][j] = mfma16(a[i], b[j], acc[i][j]);
    __syncthreads();
  }

  if (which == 2) {
    // V: transpose via LDS, then coalesced uint4 stores into vt[bh][d][t].
#pragma unroll
    for (int half = 0; half < 2; ++half) {
      __syncthreads();
      if (wn == half) {
#pragma unroll
        for (int i = 0; i < 4; i++)
#pragma unroll
          for (int j = 0; j < 4; j++)
#pragma unroll
            for (int r = 0; r < 4; r++) {
              int nloc = j * 16 + c15;                // 0..63
              int mloc = wm * 64 + i * 16 + g * 4 + r;  // 0..127
              float v = acc[i][j][r] + bv[n0 + half * 64 + nloc];
              T[nloc][mloc] = f2b(v);
            }
      }
      __syncthreads();
#pragma unroll
      for (int it = 0; it < 4; ++it) {
        int idx = it * 256 + tid;
        int row = idx >> 4;         // 0..63
        int cm = (idx & 15) * 8;    // 0..120
        int col = n0 + half * 64 + row;
        int hh = col >> 6, dd = col & 63;
        int m = m0 + cm;
        int bb2 = m >> 11, s = m & 2047;
        *(uint4*)&vt[(((bb2 * 16 + hh) * 64) + dd) * 2048 + s] =
            *(const uint4*)&T[row][cm];
      }
    }
    return;
  }

  const float* bias = (which == 0) ? bq : bk;
#pragma unroll
  for (int i = 0; i < 4; i++)
#pragma unroll
    for (int j = 0; j < 4; j++)
#pragma unroll
      for (int r = 0; r < 4; r++) {
        int row = m0 + wm * 64 + i * 16 + g * 4 + r;  // token 0..4095
        int col = n0 + wn * 64 + j * 16 + c15;        // 0..1023
        float v = acc[i][j][r] + bias[col];
        int bb = row >> 11, s = row & 2047;
        int hh = col >> 6, d = col & 63;
        if (which == 0) {
          Qcat[(((bb * 16 + hh) * 2048) + s) * 128 + d] = f2b(v * 0.0625f);
        } else {
          Kcat[(((bb * 16 + hh) * 2048) + s) * 128 + d] = f2b(v);
        }
      }
}

// ------------------------------------------------------------- helical -----
// Per (bh, 64-row s-block): hel = rows(64x64) @ Whel[h]^T (64x64) + bhel,
// normalize 2D pairs, apply scramble, write /8 into Qcat/Kcat cols [64:128).
__global__ __launch_bounds__(256, 2) void helical_kernel(
    u16* __restrict__ Qcat, u16* __restrict__ Kcat,
    const u16* __restrict__ whb, const float* __restrict__ bhel) {
  __shared__ u16 A[2][2][64][32];  // [q/k][kq][row][32]
  __shared__ u16 Wl[2][64][32];    // Whel[h] bf16, [kq][e][32]
  const int sb = blockIdx.x, bh = blockIdx.y;
  const int h = bh & 15;
  const int s0 = sb << 6;
  const int tid = threadIdx.x;
  const int wave = tid >> 6, lane = tid & 63;
  const int g = lane >> 4, c15 = lane & 15;
  u16* Qb = Qcat + (long long)bh * (2048 * 128);
  u16* Kb = Kcat + (long long)bh * (2048 * 128);

#pragma unroll
  for (int it = 0; it < 2; ++it) {  // stage Whel[h]
    int cidx = it * 256 + tid;
    int e = cidx >> 3, ds = (cidx & 7) << 3;
    uint4 vv = *(const uint4*)(whb + h * 4096 + e * 64 + ds);
    *(uint4*)&Wl[ds >> 5][e][ds & 31] = vv;
  }
#pragma unroll
  for (int it = 0; it < 4; ++it) {  // stage q (x16 to undo /16) and k rows
    int cidx = it * 256 + tid;
    int which = cidx >> 9;
    int r = (cidx >> 3) & 63;
    int ds = (cidx & 7) << 3;
    const u16* src = (which ? Kb : Qb) + (s0 + r) * 128 + ds;
    uint4 vv = *(const uint4*)src;
    if (which == 0) {
      u16 tmp[8];
      *(uint4*)tmp = vv;
#pragma unroll
      for (int q = 0; q < 8; ++q) tmp[q] = f2b(b2f(tmp[q]) * 16.0f);  // exact
      vv = *(uint4*)tmp;
    }
    *(uint4*)&A[which][ds >> 5][r][ds & 31] = vv;
  }
  __syncthreads();

  const int which = wave >> 1, hf = wave & 1;
  f32x4 acc[2][4];
#pragma unroll
  for (int i = 0; i < 2; i++)
#pragma unroll
    for (int j = 0; j < 4; j++) acc[i][j] = f32x4{0.f, 0.f, 0.f, 0.f};
#pragma unroll
  for (int kq = 0; kq < 2; ++kq) {
    bf16x8 a0 = *(const bf16x8*)&A[which][kq][hf * 32 + c15][g * 8];
    bf16x8 a1 = *(const bf16x8*)&A[which][kq][hf * 32 + 16 + c15][g * 8];
#pragma unroll
    for (int j = 0; j < 4; ++j) {
      bf16x8 bb = *(const bf16x8*)&Wl[kq][j * 16 + c15][g * 8];
      acc[0][j] = mfma16(a0, bb, acc[0][j]);
      acc[1][j] = mfma16(a1, bb, acc[1][j]);
    }
  }
  u16* Dst = which ? Kb : Qb;
#pragma unroll
  for (int i = 0; i < 2; ++i)
#pragma unroll
    for (int j = 0; j < 4; ++j)
#pragma unroll
      for (int r = 0; r < 4; ++r) {
        int s_loc = hf * 32 + i * 16 + g * 4 + r;
        int e = j * 16 + c15;
        float v = acc[i][j][r] + bhel[h * 64 + e];
        float pp = __shfl_xor(v, 1);  // pair partner (e^1), same row
        float nn = sqrtf(v * v + pp * pp);
        float o = v / fmaxf(nn, 1e-12f) * 0.125f;  // /8 (exact pow2)
        int s = s0 + s_loc;
        int u = s >> 1, c2 = s & 1;
        int row_out = ((e & 1) ? 1024 : 0) + u;
        int col_out = 64 + (e & ~1) + c2;
        Dst[row_out * 128 + col_out] = f2b(o);
      }
}

// ----------------------------------------------------------- attention -----
// Per (bh, 64-row Q-tile): each of 4 waves owns a 16-row stripe; Q fragments
// in registers. Loop over 32 K-tiles of 64: scores via K=128 MFMA, exp
// (no max needed), truncate P->bf16 into padded LDS, PV MFMA with
// pre-transposed V. den reduction DEFERRED to end (per-lane partials).
// LDS = 16 + 8 + 10 = 34.8 KB -> 4 blocks/CU; grid 1024 -> 4 blocks/CU.
__global__ __launch_bounds__(256, 4) void attn_kernel(
    const u16* __restrict__ Qcat, const u16* __restrict__ Kcat,
    const u16* __restrict__ vt, u16* __restrict__ AO) {
  __shared__ u16 Kl[4][64][32];   // [kq][t-row][32]  (gld16: no pad allowed)
  __shared__ u16 Vl[2][64][32];   // [tq][d-row][32 t]
  __shared__ u16 Pl[2][64][40];   // [tq][m-row][pad 40]  (VALU-written: padded)
  const int qt = blockIdx.x, bh = blockIdx.y;
  const int bb = bh >> 4, h = bh & 15;
  const int q0 = qt << 6;
  const int tid = threadIdx.x;
  const int wave = tid >> 6, lane = tid & 63;
  const int g = lane >> 4, c15 = lane & 15;
  const u16* Qb = Qcat + (long long)bh * (2048 * 128);
  const u16* Kb = Kcat + (long long)bh * (2048 * 128);
  const u16* Vb = vt + (long long)bh * (64 * 2048);
  const int r4 = (wave * 64 + lane) >> 2;   // 0..63
  const int c8 = (lane & 3) << 3;           // 0,8,16,24
  const int lin8 = (wave * 64 + lane) * 8;  // u16 offset for gld16 dest

  // Q fragments for this wave's 16-row stripe (4 x 16B per lane)
  bf16x8 qf[4];
#pragma unroll
  for (int kq = 0; kq < 4; ++kq)
    qf[kq] = *(const bf16x8*)(Qb + (q0 + wave * 16 + c15) * 128 + kq * 32 +
                              g * 8);

  f32x4 accO[4];
  float den[4];
#pragma unroll
  for (int j = 0; j < 4; j++) accO[j] = f32x4{0.f, 0.f, 0.f, 0.f};
#pragma unroll
  for (int r = 0; r < 4; r++) den[r] = 0.f;

  for (int t = 0; t < 32; ++t) {
    const int t0 = t << 6;
#pragma unroll
    for (int kq = 0; kq < 4; ++kq)
      gld16(((u16*)Kl) + kq * 2048 + lin8, Kb + (t0 + r4) * 128 + kq * 32 + c8);
#pragma unroll
    for (int tq = 0; tq < 2; ++tq)
      gld16(((u16*)Vl) + tq * 2048 + lin8, Vb + r4 * 2048 + t0 + tq * 32 + c8);
    __syncthreads();

    // scores: S[m][t'] = sum_128 Qcat*Kcat  (scales pre-folded)
    f32x4 accS[4];
#pragma unroll
    for (int j = 0; j < 4; j++) accS[j] = f32x4{0.f, 0.f, 0.f, 0.f};
#pragma unroll
    for (int kq = 0; kq < 4; ++kq) {
#pragma unroll
      for (int j = 0; j < 4; ++j) {
        bf16x8 bk2 = *(const bf16x8*)&Kl[kq][j * 16 + c15][g * 8];
        accS[j] = mfma16(qf[kq], bk2, accS[j]);
      }
    }

    // exp; accumulate per-lane den partials; truncate-convert P into LDS
#pragma unroll
    for (int j = 0; j < 4; ++j) {
      int tq = j >> 1;
      int tc = ((j & 1) << 4) + c15;
      int mrow = wave * 16 + g * 4;
#pragma unroll
      for (int r = 0; r < 4; ++r) {
        float p = __expf(accS[j][r]);
        den[r] += p;
        Pl[tq][mrow + r][tc] = (u16)(__float_as_uint(p) >> 16);  // truncate
      }
    }

    // O += P @ V   (P rows are per-wave private -> no barrier needed)
#pragma unroll
    for (int tq = 0; tq < 2; ++tq) {
      bf16x8 a = *(const bf16x8*)&Pl[tq][wave * 16 + c15][g * 8];
#pragma unroll
      for (int j = 0; j < 4; ++j) {
        bf16x8 bv2 = *(const bf16x8*)&Vl[tq][j * 16 + c15][g * 8];
        accO[j] = mfma16(a, bv2, accO[j]);
      }
    }
    __syncthreads();
  }

  // final den reduction over the 16 t'-columns held across c15 lanes
#pragma unroll
  for (int r = 0; r < 4; ++r) {
    float v = den[r];
    v += __shfl_xor(v, 1);
    v += __shfl_xor(v, 2);
    v += __shfl_xor(v, 4);
    v += __shfl_xor(v, 8);
    den[r] = v;
  }

#pragma unroll
  for (int j = 0; j < 4; ++j)
#pragma unroll
    for (int r = 0; r < 4; ++r) {
      int s = q0 + wave * 16 + g * 4 + r;
      float o = accO[j][r] / den[r];
      int d = j * 16 + c15;
      AO[((bb * 2048 + s) * 1024) + h * 64 + d] = f2b(o);
    }
}

// ----------------------------------------------------------- out GEMM -----
__global__ __launch_bounds__(256, 2) void out_gemm(
    const u16* __restrict__ AO, const u16* __restrict__ wob,
    const float* __restrict__ bo, float* __restrict__ out) {
  __shared__ u16 Al[128][32];
  __shared__ u16 Bl[128][32];
  const int n0 = blockIdx.x << 7;
  const int m0 = blockIdx.y << 7;
  const int tid = threadIdx.x;
  const int wave = tid >> 6, lane = tid & 63;
  const int g = lane >> 4, c15 = lane & 15;
  const int wm = wave & 1, wn = wave >> 1;
  const u16* Wp = wob + n0 * 1024;
  const u16* Ap = AO + m0 * 1024;
  const int srow = (wave * 64 + lane) >> 2;
  const int scol = (lane & 3) << 3;

  f32x4 acc[4][4];
#pragma unroll
  for (int i = 0; i < 4; i++)
#pragma unroll
    for (int j = 0; j < 4; j++) acc[i][j] = f32x4{0.f, 0.f, 0.f, 0.f};

  for (int k0 = 0; k0 < 1024; k0 += 32) {
    gld16(&Al[srow][scol],      Ap + srow * 1024 + k0 + scol);
    gld16(&Al[64 + srow][scol], Ap + (64 + srow) * 1024 + k0 + scol);
    gld16(&Bl[srow][scol],      Wp + srow * 1024 + k0 + scol);
    gld16(&Bl[64 + srow][scol], Wp + (64 + srow) * 1024 + k0 + scol);
    __syncthreads();
    bf16x8 a[4], b[4];
#pragma unroll
    for (int i = 0; i < 4; i++)
      a[i] = *(const bf16x8*)&Al[wm * 64 + i * 16 + c15][g * 8];
#pragma unroll
    for (int j = 0; j < 4; j++)
      b[j] = *(const bf16x8*)&Bl[wn * 64 + j * 16 + c15][g * 8];
#pragma unroll
    for (int i = 0; i < 4; i++)
#pragma unroll
      for (int j = 0; j < 4; j++) acc[i][j] = mfma16(a[i], b[j], acc[i][j]);
    __syncthreads();
  }
#pragma unroll
  for (int i = 0; i < 4; i++)
#pragma unroll
    for (int j = 0; j < 4; j++)
#pragma unroll
      for (int r = 0; r < 4; r++) {
        int row = m0 + wm * 64 + i * 16 + g * 4 + r;
        int col = n0 + wn * 64 + j * 16 + c15;
        out[row * 1024 + col] = acc[i][j][r] + bo[col];
      }
}

// -------------------------------------------------------------- launch -----
extern "C" void kernel_launch(void* const* d_in, const int* in_sizes, int n_in,
                              void* d_out, int out_size, void* d_ws,
                              size_t ws_size, hipStream_t stream) {
  const float* x    = (const float*)d_in[0];
  const float* Wq   = (const float*)d_in[1];
  const float* bq   = (const float*)d_in[2];
  const float* Wk   = (const float*)d_in[3];
  const float* bk   = (const float*)d_in[4];
  const float* Wv   = (const float*)d_in[5];
  const float* bv   = (const float*)d_in[6];
  const float* Wo   = (const float*)d_in[7];
  const float* bo   = (const float*)d_in[8];
  const float* Whel = (const float*)d_in[9];
  const float* bhel = (const float*)d_in[10];
  float* out = (float*)d_out;

  char* ws = (char*)d_ws;
  u16* xb   = (u16*)(ws + 0);                  //  8 MB
  u16* wb   = (u16*)(ws + 8388608);            //  6 MB (Wq|Wk|Wv)
  u16* wob  = (u16*)(ws + 14680064);           //  2 MB
  u16* whb  = (u16*)(ws + 16777216);           //  128 KB
  u16* Qcat = (u16*)(ws + 16908288);           // 16 MB  [bh][s][128]
  u16* Kcat = (u16*)(ws + 33685504);           // 16 MB
  u16* vt   = (u16*)(ws + 50462720);           //  8 MB  [bh][d][t]
  u16* AO   = (u16*)(ws + 58851328);           //  8 MB  (total ~64.1 MB)

  dim3 blk(256);
  cast_kernel<<<dim3(8256), blk, 0, stream>>>(x, Wq, Wk, Wv, Wo, Whel, xb, wb,
                                              wob, whb);
  qkv_gemm<<<dim3(24, 32), blk, 0, stream>>>(xb, wb, bq, bk, bv, Qcat, Kcat,
                                             vt);
  helical_kernel<<<dim3(32, 32), blk, 0, stream>>>(Qcat, Kcat, whb, bhel);
  attn_kernel<<<dim3(32, 32), blk, 0, stream>>>(Qcat, Kcat, vt, AO);
  out_gemm<<<dim3(8, 32), blk, 0, stream>>>(AO, wob, bo, out);
}

// Round 3
// 236.027 us; speedup vs baseline: 1.1442x; 1.0789x over previous
//
#include <hip/hip_runtime.h>
#include <hip/hip_bf16.h>

// HelicalAttention on MI355X (gfx950).
// B=2,S=2048,E=1024,H=16,HD=64,HX=64,P=32. All heavy math in bf16 MFMA,
// fp32 accumulate. Score = (q/16)·k + (qs/8)·(ks/8) folded into one K=128
// contraction; log2(e) additionally folded into the Q-side so softmax uses
// raw exp2. Flash-style, no max subtraction (scores bounded ~|2.5·log2e|).
// R3: attn restructured around 32x32x16 MFMA computing S^T = K·Q^T
// (Q in registers as B-operand), packed b64 P-writes, XOR-swizzled K/V
// staging (gld16 per-lane source permutation) -> LDS-pipe pressure halved.

typedef unsigned short u16;
typedef unsigned int u32;
typedef __attribute__((ext_vector_type(8))) __bf16 bf16x8;
typedef __attribute__((ext_vector_type(4))) float f32x4;
typedef __attribute__((ext_vector_type(16))) float f32x16;

__device__ __forceinline__ u16 f2b(float f) {
  u32 u = __float_as_uint(f);
  u32 r = (u + 0x7fffu + ((u >> 16) & 1u)) >> 16;
  return (u16)r;
}
__device__ __forceinline__ float b2f(u16 h) {
  return __uint_as_float(((u32)h) << 16);
}

__device__ __forceinline__ f32x4 mfma16(bf16x8 a, bf16x8 b, f32x4 c) {
  return __builtin_amdgcn_mfma_f32_16x16x32_bf16(a, b, c, 0, 0, 0);
}
__device__ __forceinline__ f32x16 mfma32(bf16x8 a, bf16x8 b, f32x16 c) {
  return __builtin_amdgcn_mfma_f32_32x32x16_bf16(a, b, c, 0, 0, 0);
}

// async global->LDS, 16B per lane. LDS dest = wave-uniform base + lane*16.
__device__ __forceinline__ void gld16(void* lds, const void* g) {
  __builtin_amdgcn_global_load_lds(
      (const __attribute__((address_space(1))) unsigned int*)g,
      (__attribute__((address_space(3))) unsigned int*)lds, 16, 0, 0);
}

#define LOG2E 1.4426950408889634f

// ---------------------------------------------------------------- cast -----
__global__ __launch_bounds__(256) void cast_kernel(
    const float* __restrict__ x,  const float* __restrict__ wq,
    const float* __restrict__ wk, const float* __restrict__ wv,
    const float* __restrict__ wo, const float* __restrict__ whel,
    u16* __restrict__ xb, u16* __restrict__ wb, u16* __restrict__ wob,
    u16* __restrict__ whb) {
  long long q = (long long)blockIdx.x * 256 + threadIdx.x;
  const float* s; u16* d; long long base;
  if (q < 1048576)      { s = x;    d = xb;            base = 0; }
  else if (q < 1310720) { s = wq;   d = wb;            base = 1048576; }
  else if (q < 1572864) { s = wk;   d = wb + 1048576;  base = 1310720; }
  else if (q < 1835008) { s = wv;   d = wb + 2097152;  base = 1572864; }
  else if (q < 2097152) { s = wo;   d = wob;           base = 1835008; }
  else                  { s = whel; d = whb;           base = 2097152; }
  long long e = (q - base) * 4;
  float4 v = *(const float4*)(s + e);
  ushort4 o;
  o.x = f2b(v.x); o.y = f2b(v.y); o.z = f2b(v.z); o.w = f2b(v.w);
  *(ushort4*)(d + e) = o;
}

// ------------------------------------------------------------ QKV GEMM -----
// which=0 -> Qcat[bh][s][0:64] = q*(log2e/16); which=1 -> Kcat = k;
// which=2 -> vT[bh][d][t] = v via LDS transpose (coalesced stores).
__global__ __launch_bounds__(256, 2) void qkv_gemm(
    const u16* __restrict__ xb, const u16* __restrict__ wb,
    const float* __restrict__ bq, const float* __restrict__ bk,
    const float* __restrict__ bv,
    u16* __restrict__ Qcat, u16* __restrict__ Kcat, u16* __restrict__ vt) {
  __shared__ u16 Al[128][32];
  __shared__ u16 Bl[128][32];
  __shared__ u16 T[64][136];  // transpose staging for V (padded, 16B rows)
  const int nt = blockIdx.x, mt = blockIdx.y;
  const int which = nt >> 3;
  const int n0 = (nt & 7) << 7;
  const int m0 = mt << 7;
  const int tid = threadIdx.x;
  const int wave = tid >> 6, lane = tid & 63;
  const int g = lane >> 4, c15 = lane & 15;
  const int wm = wave & 1, wn = wave >> 1;
  const u16* Wp = wb + (long long)which * (1024 * 1024) + n0 * 1024;
  const u16* Ap = xb + m0 * 1024;
  const int srow = (wave * 64 + lane) >> 2;  // 0..63
  const int scol = (lane & 3) << 3;          // 0,8,16,24

  f32x4 acc[4][4];
#pragma unroll
  for (int i = 0; i < 4; i++)
#pragma unroll
    for (int j = 0; j < 4; j++) acc[i][j] = f32x4{0.f, 0.f, 0.f, 0.f};

  for (int k0 = 0; k0 < 1024; k0 += 32) {
    gld16(&Al[srow][scol],      Ap + srow * 1024 + k0 + scol);
    gld16(&Al[64 + srow][scol], Ap + (64 + srow) * 1024 + k0 + scol);
    gld16(&Bl[srow][scol],      Wp + srow * 1024 + k0 + scol);
    gld16(&Bl[64 + srow][scol], Wp + (64 + srow) * 1024 + k0 + scol);
    __syncthreads();
    bf16x8 a[4], b[4];
#pragma unroll
    for (int i = 0; i < 4; i++)
      a[i] = *(const bf16x8*)&Al[wm * 64 + i * 16 + c15][g * 8];
#pragma unroll
    for (int j = 0; j < 4; j++)
      b[j] = *(const bf16x8*)&Bl[wn * 64 + j * 16 + c15][g * 8];
#pragma unroll
    for (int i = 0; i < 4; i++)
#pragma unroll
      for (int j = 0; j < 4; j++) acc[i][j] = mfma16(a[i], b[j], acc[i][j]);
    __syncthreads();
  }

  if (which == 2) {
#pragma unroll
    for (int half = 0; half < 2; ++half) {
      __syncthreads();
      if (wn == half) {
#pragma unroll
        for (int i = 0; i < 4; i++)
#pragma unroll
          for (int j = 0; j < 4; j++)
#pragma unroll
            for (int r = 0; r < 4; r++) {
              int nloc = j * 16 + c15;                  // 0..63
              int mloc = wm * 64 + i * 16 + g * 4 + r;  // 0..127
              float v = acc[i][j][r] + bv[n0 + half * 64 + nloc];
              T[nloc][mloc] = f2b(v);
            }
      }
      __syncthreads();
#pragma unroll
      for (int it = 0; it < 4; ++it) {
        int idx = it * 256 + tid;
        int row = idx >> 4;         // 0..63
        int cm = (idx & 15) * 8;    // 0..120
        int col = n0 + half * 64 + row;
        int hh = col >> 6, dd = col & 63;
        int m = m0 + cm;
        int bb2 = m >> 11, s = m & 2047;
        *(uint4*)&vt[(((bb2 * 16 + hh) * 64) + dd) * 2048 + s] =
            *(const uint4*)&T[row][cm];
      }
    }
    return;
  }

  const float* bias = (which == 0) ? bq : bk;
#pragma unroll
  for (int i = 0; i < 4; i++)
#pragma unroll
    for (int j = 0; j < 4; j++)
#pragma unroll
      for (int r = 0; r < 4; r++) {
        int row = m0 + wm * 64 + i * 16 + g * 4 + r;  // token 0..4095
        int col = n0 + wn * 64 + j * 16 + c15;        // 0..1023
        float v = acc[i][j][r] + bias[col];
        int bb = row >> 11, s = row & 2047;
        int hh = col >> 6, d = col & 63;
        if (which == 0) {
          // q * log2e/16 (log2e folded for exp2 softmax)
          Qcat[(((bb * 16 + hh) * 2048) + s) * 128 + d] =
              f2b(v * (0.0625f * LOG2E));
        } else {
          Kcat[(((bb * 16 + hh) * 2048) + s) * 128 + d] = f2b(v);
        }
      }
}

// ------------------------------------------------------------- helical -----
// Q-side outputs carry an extra log2e (K-side plain), matching qkv fold.
__global__ __launch_bounds__(256, 2) void helical_kernel(
    u16* __restrict__ Qcat, u16* __restrict__ Kcat,
    const u16* __restrict__ whb, const float* __restrict__ bhel) {
  __shared__ u16 A[2][2][64][32];  // [q/k][kq][row][32]
  __shared__ u16 Wl[2][64][32];    // Whel[h] bf16, [kq][e][32]
  const int sb = blockIdx.x, bh = blockIdx.y;
  const int h = bh & 15;
  const int s0 = sb << 6;
  const int tid = threadIdx.x;
  const int wave = tid >> 6, lane = tid & 63;
  const int g = lane >> 4, c15 = lane & 15;
  u16* Qb = Qcat + (long long)bh * (2048 * 128);
  u16* Kb = Kcat + (long long)bh * (2048 * 128);

#pragma unroll
  for (int it = 0; it < 2; ++it) {  // stage Whel[h]
    int cidx = it * 256 + tid;
    int e = cidx >> 3, ds = (cidx & 7) << 3;
    uint4 vv = *(const uint4*)(whb + h * 4096 + e * 64 + ds);
    *(uint4*)&Wl[ds >> 5][e][ds & 31] = vv;
  }
#pragma unroll
  for (int it = 0; it < 4; ++it) {  // stage q (x 16/log2e to undo) and k rows
    int cidx = it * 256 + tid;
    int which = cidx >> 9;
    int r = (cidx >> 3) & 63;
    int ds = (cidx & 7) << 3;
    const u16* src = (which ? Kb : Qb) + (s0 + r) * 128 + ds;
    uint4 vv = *(const uint4*)src;
    if (which == 0) {
      u16 tmp[8];
      *(uint4*)tmp = vv;
#pragma unroll
      for (int q = 0; q < 8; ++q)
        tmp[q] = f2b(b2f(tmp[q]) * (16.0f / LOG2E));
      vv = *(uint4*)tmp;
    }
    *(uint4*)&A[which][ds >> 5][r][ds & 31] = vv;
  }
  __syncthreads();

  const int which = wave >> 1, hf = wave & 1;
  f32x4 acc[2][4];
#pragma unroll
  for (int i = 0; i < 2; i++)
#pragma unroll
    for (int j = 0; j < 4; j++) acc[i][j] = f32x4{0.f, 0.f, 0.f, 0.f};
#pragma unroll
  for (int kq = 0; kq < 2; ++kq) {
    bf16x8 a0 = *(const bf16x8*)&A[which][kq][hf * 32 + c15][g * 8];
    bf16x8 a1 = *(const bf16x8*)&A[which][kq][hf * 32 + 16 + c15][g * 8];
#pragma unroll
    for (int j = 0; j < 4; ++j) {
      bf16x8 bb = *(const bf16x8*)&Wl[kq][j * 16 + c15][g * 8];
      acc[0][j] = mfma16(a0, bb, acc[0][j]);
      acc[1][j] = mfma16(a1, bb, acc[1][j]);
    }
  }
  u16* Dst = which ? Kb : Qb;
  const float oscale = which ? 0.125f : (0.125f * LOG2E);
#pragma unroll
  for (int i = 0; i < 2; ++i)
#pragma unroll
    for (int j = 0; j < 4; ++j)
#pragma unroll
      for (int r = 0; r < 4; ++r) {
        int s_loc = hf * 32 + i * 16 + g * 4 + r;
        int e = j * 16 + c15;
        float v = acc[i][j][r] + bhel[h * 64 + e];
        float pp = __shfl_xor(v, 1);  // pair partner (e^1), same row
        float nn = sqrtf(v * v + pp * pp);
        float o = v / fmaxf(nn, 1e-12f) * oscale;
        int s = s0 + s_loc;
        int u = s >> 1, c2 = s & 1;
        int row_out = ((e & 1) ? 1024 : 0) + u;
        int col_out = 64 + (e & ~1) + c2;
        Dst[row_out * 128 + col_out] = f2b(o);
      }
}

// ----------------------------------------------------------- attention -----
// Per (bh, 64-q tile), 4 waves as (wq, wt) in 2x2. Per 64-t iter:
//   S^T[t][q] = K·Q^T via 8x mfma_32x32x16 (A = K-frag from swizzled LDS,
//   B = Q-frag in registers). C-layout gives each lane a fixed q-column ->
//   den is a per-lane scalar; P^T rows pack to b64 LDS writes (Pl[q][t]).
//   O[q][d] = P·V via 4x mfma_32x32x16 (A = Pl rows, B = V-frag from
//   swizzled Vl[d][t]). 3 barriers/iter. LDS ~33.8 KB -> 4 blocks/CU,
//   grid 1024 -> 4 blocks/CU.
__global__ __launch_bounds__(256, 4) void attn_kernel(
    const u16* __restrict__ Qcat, const u16* __restrict__ Kcat,
    const u16* __restrict__ vt, u16* __restrict__ AO) {
  __shared__ u16 Kl[4][64][32];  // [kq][t-row][4 chunks16, XOR-swizzled]
  __shared__ u16 Vl[2][64][32];  // [tq][d-row][4 chunks16, XOR-swizzled]
  __shared__ u16 Pl[64][68];     // [q][t] bf16, 17-dword rows (bank bijection)
  __shared__ float denl[2][64];  // [wt][q-local]
  const int qt = blockIdx.x, bh = blockIdx.y;
  const int bb = bh >> 4, h = bh & 15;
  const int q0 = qt << 6;
  const int tid = threadIdx.x;
  const int w = tid >> 6, lane = tid & 63;
  const int wq = w & 1, wt = w >> 1;
  const int l31 = lane & 31, l5 = lane >> 5;
  const u16* Qb = Qcat + (long long)bh * (2048 * 128);
  const u16* Kb = Kcat + (long long)bh * (2048 * 128);
  const u16* Vb = vt + (long long)bh * (64 * 2048);

  const int srow = lane >> 2;  // staging: row within 16-row group
  const int sc = lane & 3;     // staging: chunk slot

  // Q fragments (B-operand): n = l31 -> q = q0+32wq+l31; k = ks*16+l5*8+j
  bf16x8 qf[8];
  {
    const u16* qrow = Qb + (q0 + 32 * wq + l31) * 128 + l5 * 8;
#pragma unroll
    for (int ks = 0; ks < 8; ++ks) qf[ks] = *(const bf16x8*)(qrow + ks * 16);
  }

  f32x16 accO;
#pragma unroll
  for (int i = 0; i < 16; ++i) accO[i] = 0.f;
  float den = 0.f;

  for (int t = 0; t < 32; ++t) {
    const int t0 = t << 6;
    // ---- stage K (wave w: kq=w, 4 row-groups) with XOR swizzle
#pragma unroll
    for (int rg = 0; rg < 4; ++rg) {
      int row = rg * 16 + srow;
      int cc = sc ^ ((row >> 1) & 3);
      gld16(((u16*)Kl) + w * 2048 + rg * 512 + lane * 8,
            Kb + (t0 + row) * 128 + w * 32 + cc * 8);
    }
    // ---- stage V (wave w: d-rows [16w,16w+16), both t-halves)
    {
      int drow = w * 16 + srow;
      int cc = sc ^ ((drow >> 1) & 3);
#pragma unroll
      for (int tq = 0; tq < 2; ++tq)
        gld16(((u16*)Vl) + tq * 2048 + w * 512 + lane * 8,
              Vb + drow * 2048 + t0 + tq * 32 + cc * 8);
    }
    __syncthreads();

    // ---- S^T quadrant [32wt..][32wq..]: 8 k-steps of 16 over cat=128
    f32x16 accS;
#pragma unroll
    for (int i = 0; i < 16; ++i) accS[i] = 0.f;
    {
      const int row = 32 * wt + l31;
      const int sw = (row >> 1) & 3;
#pragma unroll
      for (int ks = 0; ks < 8; ++ks) {
        int cp = (2 * (ks & 1) + l5) ^ sw;
        bf16x8 ak = *(const bf16x8*)&Kl[ks >> 1][row][cp * 8];
        accS = mfma32(ak, qf[ks], accS);
      }
    }

    // ---- exp2, den partial, pack P^T -> Pl[q][t] (b64 writes)
#pragma unroll
    for (int rr = 0; rr < 4; ++rr) {
      u16 pk[4];
#pragma unroll
      for (int r2 = 0; r2 < 4; ++r2) {
        float p = __builtin_amdgcn_exp2f(accS[rr * 4 + r2]);
        den += p;
        pk[r2] = (u16)(__float_as_uint(p) >> 16);  // truncate to bf16
      }
      // t-local rows r2 + 8*rr + 4*l5 (consecutive r2) at q-col 32wq+l31
      *(uint2*)&Pl[32 * wq + l31][32 * wt + 8 * rr + 4 * l5] =
          *(const uint2*)pk;
    }
    __syncthreads();

    // ---- O quadrant [q:32wq..][d:32wt..] += P·V, 4 k-steps of 16 over t=64
    {
      const int drow = 32 * wt + l31;
      const int sw = (drow >> 1) & 3;
#pragma unroll
      for (int ks = 0; ks < 4; ++ks) {
        bf16x8 ap = *(const bf16x8*)&Pl[32 * wq + l31][ks * 16 + l5 * 8];
        int ct = 2 * ks + l5;
        bf16x8 bvf = *(const bf16x8*)&Vl[ct >> 2][drow][((ct & 3) ^ sw) * 8];
        accO = mfma32(ap, bvf, accO);
      }
    }
    __syncthreads();
  }

  // ---- den: lane holds partial for q-col (32wq+l31) over its 16 t-rows/iter
  den += __shfl_xor(den, 32);
  if (lane < 32) denl[wt][32 * wq + lane] = den;
  __syncthreads();

#pragma unroll
  for (int r = 0; r < 16; ++r) {
    int q_loc = 32 * wq + (r & 3) + 8 * (r >> 2) + 4 * l5;
    float dfull = denl[0][q_loc] + denl[1][q_loc];
    float o = accO[r] / dfull;
    int q = q0 + q_loc;
    int d = h * 64 + 32 * wt + l31;
    AO[((bb * 2048 + q) * 1024) + d] = f2b(o);
  }
}

// ----------------------------------------------------------- out GEMM -----
__global__ __launch_bounds__(256, 2) void out_gemm(
    const u16* __restrict__ AO, const u16* __restrict__ wob,
    const float* __restrict__ bo, float* __restrict__ out) {
  __shared__ u16 Al[128][32];
  __shared__ u16 Bl[128][32];
  const int n0 = blockIdx.x << 7;
  const int m0 = blockIdx.y << 7;
  const int tid = threadIdx.x;
  const int wave = tid >> 6, lane = tid & 63;
  const int g = lane >> 4, c15 = lane & 15;
  const int wm = wave & 1, wn = wave >> 1;
  const u16* Wp = wob + n0 * 1024;
  const u16* Ap = AO + m0 * 1024;
  const int srow = (wave * 64 + lane) >> 2;
  const int scol = (lane & 3) << 3;

  f32x4 acc[4][4];
#pragma unroll
  for (int i = 0; i < 4; i++)
#pragma unroll
    for (int j = 0; j < 4; j++) acc[i][j] = f32x4{0.f, 0.f, 0.f, 0.f};

  for (int k0 = 0; k0 < 1024; k0 += 32) {
    gld16(&Al[srow][scol],      Ap + srow * 1024 + k0 + scol);
    gld16(&Al[64 + srow][scol], Ap + (64 + srow) * 1024 + k0 + scol);
    gld16(&Bl[srow][scol],      Wp + srow * 1024 + k0 + scol);
    gld16(&Bl[64 + srow][scol], Wp + (64 + srow) * 1024 + k0 + scol);
    __syncthreads();
    bf16x8 a[4], b[4];
#pragma unroll
    for (int i = 0; i < 4; i++)
      a[i] = *(const bf16x8*)&Al[wm * 64 + i * 16 + c15][g * 8];
#pragma unroll
    for (int j = 0; j < 4; j++)
      b[j] = *(const bf16x8*)&Bl[wn * 64 + j * 16 + c15][g * 8];
#pragma unroll
    for (int i = 0; i < 4; i++)
#pragma unroll
      for (int j = 0; j < 4; j++) acc[i][j] = mfma16(a[i], b[j], acc[i][j]);
    __syncthreads();
  }
#pragma unroll
  for (int i = 0; i < 4; i++)
#pragma unroll
    for (int j = 0; j < 4; j++)
#pragma unroll
      for (int r = 0; r < 4; r++) {
        int row = m0 + wm * 64 + i * 16 + g * 4 + r;
        int col = n0 + wn * 64 + j * 16 + c15;
        out[row * 1024 + col] = acc[i][j][r] + bo[col];
      }
}

// -------------------------------------------------------------- launch -----
extern "C" void kernel_launch(void* const* d_in, const int* in_sizes, int n_in,
                              void* d_out, int out_size, void* d_ws,
                              size_t ws_size, hipStream_t stream) {
  const float* x    = (const float*)d_in[0];
  const float* Wq   = (const float*)d_in[1];
  const float* bq   = (const float*)d_in[2];
  const float* Wk   = (const float*)d_in[3];
  const float* bk   = (const float*)d_in[4];
  const float* Wv   = (const float*)d_in[5];
  const float* bv   = (const float*)d_in[6];
  const float* Wo   = (const float*)d_in[7];
  const float* bo   = (const float*)d_in[8];
  const float* Whel = (const float*)d_in[9];
  const float* bhel = (const float*)d_in[10];
  float* out = (float*)d_out;

  char* ws = (char*)d_ws;
  u16* xb   = (u16*)(ws + 0);                  //  8 MB
  u16* wb   = (u16*)(ws + 8388608);            //  6 MB (Wq|Wk|Wv)
  u16* wob  = (u16*)(ws + 14680064);           //  2 MB
  u16* whb  = (u16*)(ws + 16777216);           //  128 KB
  u16* Qcat = (u16*)(ws + 16908288);           // 16 MB  [bh][s][128]
  u16* Kcat = (u16*)(ws + 33685504);           // 16 MB
  u16* vt   = (u16*)(ws + 50462720);           //  8 MB  [bh][d][t]
  u16* AO   = (u16*)(ws + 58851328);           //  8 MB  (total ~64.1 MB)

  dim3 blk(256);
  cast_kernel<<<dim3(8256), blk, 0, stream>>>(x, Wq, Wk, Wv, Wo, Whel, xb, wb,
                                              wob, whb);
  qkv_gemm<<<dim3(24, 32), blk, 0, stream>>>(xb, wb, bq, bk, bv, Qcat, Kcat,
                                             vt);
  helical_kernel<<<dim3(32, 32), blk, 0, stream>>>(Qcat, Kcat, whb, bhel);
  attn_kernel<<<dim3(32, 32), blk, 0, stream>>>(Qcat, Kcat, vt, AO);
  out_gemm<<<dim3(8, 32), blk, 0, stream>>>(AO, wob, bo, out);
}

// Round 4
// 226.379 us; speedup vs baseline: 1.1930x; 1.0426x over previous
//
#include <hip/hip_runtime.h>
#include <hip/hip_bf16.h>

// HelicalAttention on MI355X (gfx950).
// B=2,S=2048,E=1024,H=16,HD=64,HX=64,P=32. All heavy math in bf16 MFMA,
// fp32 accumulate. Score = (q/16)·k + (qs/8)·(ks/8) folded into one K=128
// contraction; log2(e) folded into Q so softmax uses raw exp2. Flash-style,
// no max subtraction (scores bounded).
// R4: attn = single-barrier pipelined K-loop (double-buffered K/V, prefetch
// issued AFTER the barrier so the vmcnt(0) drain hits a load that had a full
// compute phase in flight), P kept in registers (shfl-based C->A relayout),
// per-wave t-half O partials summed once at the end. qkv/out GEMMs get the
// same prefetch-after-barrier double-buffer retrofit.

typedef unsigned short u16;
typedef unsigned int u32;
typedef __attribute__((ext_vector_type(8))) __bf16 bf16x8;
typedef __attribute__((ext_vector_type(4))) float f32x4;
typedef __attribute__((ext_vector_type(16))) float f32x16;

union BFrag { u32 u[4]; bf16x8 b; };

__device__ __forceinline__ u16 f2b(float f) {
  u32 u = __float_as_uint(f);
  u32 r = (u + 0x7fffu + ((u >> 16) & 1u)) >> 16;
  return (u16)r;
}
__device__ __forceinline__ float b2f(u16 h) {
  return __uint_as_float(((u32)h) << 16);
}

__device__ __forceinline__ f32x4 mfma16(bf16x8 a, bf16x8 b, f32x4 c) {
  return __builtin_amdgcn_mfma_f32_16x16x32_bf16(a, b, c, 0, 0, 0);
}
__device__ __forceinline__ f32x16 mfma32(bf16x8 a, bf16x8 b, f32x16 c) {
  return __builtin_amdgcn_mfma_f32_32x32x16_bf16(a, b, c, 0, 0, 0);
}

// async global->LDS, 16B per lane. LDS dest = wave-uniform base + lane*16.
__device__ __forceinline__ void gld16(void* lds, const void* g) {
  __builtin_amdgcn_global_load_lds(
      (const __attribute__((address_space(1))) unsigned int*)g,
      (__attribute__((address_space(3))) unsigned int*)lds, 16, 0, 0);
}

#define LOG2E 1.4426950408889634f

// ---------------------------------------------------------------- cast -----
__global__ __launch_bounds__(256) void cast_kernel(
    const float* __restrict__ x,  const float* __restrict__ wq,
    const float* __restrict__ wk, const float* __restrict__ wv,
    const float* __restrict__ wo, const float* __restrict__ whel,
    u16* __restrict__ xb, u16* __restrict__ wb, u16* __restrict__ wob,
    u16* __restrict__ whb) {
  long long q = (long long)blockIdx.x * 256 + threadIdx.x;
  const float* s; u16* d; long long base;
  if (q < 1048576)      { s = x;    d = xb;            base = 0; }
  else if (q < 1310720) { s = wq;   d = wb;            base = 1048576; }
  else if (q < 1572864) { s = wk;   d = wb + 1048576;  base = 1310720; }
  else if (q < 1835008) { s = wv;   d = wb + 2097152;  base = 1572864; }
  else if (q < 2097152) { s = wo;   d = wob;           base = 1835008; }
  else                  { s = whel; d = whb;           base = 2097152; }
  long long e = (q - base) * 4;
  float4 v = *(const float4*)(s + e);
  ushort4 o;
  o.x = f2b(v.x); o.y = f2b(v.y); o.z = f2b(v.z); o.w = f2b(v.w);
  *(ushort4*)(d + e) = o;
}

// ------------------------------------------------------------ QKV GEMM -----
// which=0 -> Qcat[bh][s][0:64] = q*(log2e/16); which=1 -> Kcat = k;
// which=2 -> vT[bh][d][t] = v via LDS transpose (coalesced stores).
// Double-buffered LDS, prefetch-after-barrier pipeline (1 barrier/K-step).
__global__ __launch_bounds__(256, 3) void qkv_gemm(
    const u16* __restrict__ xb, const u16* __restrict__ wb,
    const float* __restrict__ bq, const float* __restrict__ bk,
    const float* __restrict__ bv,
    u16* __restrict__ Qcat, u16* __restrict__ Kcat, u16* __restrict__ vt) {
  __shared__ u16 Al[2][128][32];
  __shared__ u16 Bl[2][128][32];
  __shared__ u16 T[64][136];  // V transpose staging (epilogue only)
  const int nt = blockIdx.x, mt = blockIdx.y;
  const int which = nt >> 3;
  const int n0 = (nt & 7) << 7;
  const int m0 = mt << 7;
  const int tid = threadIdx.x;
  const int wave = tid >> 6, lane = tid & 63;
  const int g = lane >> 4, c15 = lane & 15;
  const int wm = wave & 1, wn = wave >> 1;
  const u16* Wp = wb + (long long)which * (1024 * 1024) + n0 * 1024;
  const u16* Ap = xb + m0 * 1024;
  const int srow = (wave * 64 + lane) >> 2;  // 0..63
  const int scol = (lane & 3) << 3;          // 0,8,16,24

  f32x4 acc[4][4];
#pragma unroll
  for (int i = 0; i < 4; i++)
#pragma unroll
    for (int j = 0; j < 4; j++) acc[i][j] = f32x4{0.f, 0.f, 0.f, 0.f};

  // prologue: stage k0=0 into buf 0
  gld16(&Al[0][srow][scol],      Ap + srow * 1024 + scol);
  gld16(&Al[0][64 + srow][scol], Ap + (64 + srow) * 1024 + scol);
  gld16(&Bl[0][srow][scol],      Wp + srow * 1024 + scol);
  gld16(&Bl[0][64 + srow][scol], Wp + (64 + srow) * 1024 + scol);

  for (int k0 = 0; k0 < 1024; k0 += 32) {
    const int c = (k0 >> 5) & 1;
    __syncthreads();  // waits DMA(k0); prefetch below had full compute to land
    if (k0 + 32 < 1024) {
      const int kn = k0 + 32;
      gld16(&Al[c ^ 1][srow][scol],      Ap + srow * 1024 + kn + scol);
      gld16(&Al[c ^ 1][64 + srow][scol], Ap + (64 + srow) * 1024 + kn + scol);
      gld16(&Bl[c ^ 1][srow][scol],      Wp + srow * 1024 + kn + scol);
      gld16(&Bl[c ^ 1][64 + srow][scol], Wp + (64 + srow) * 1024 + kn + scol);
    }
    bf16x8 a[4], b[4];
#pragma unroll
    for (int i = 0; i < 4; i++)
      a[i] = *(const bf16x8*)&Al[c][wm * 64 + i * 16 + c15][g * 8];
#pragma unroll
    for (int j = 0; j < 4; j++)
      b[j] = *(const bf16x8*)&Bl[c][wn * 64 + j * 16 + c15][g * 8];
#pragma unroll
    for (int i = 0; i < 4; i++)
#pragma unroll
      for (int j = 0; j < 4; j++) acc[i][j] = mfma16(a[i], b[j], acc[i][j]);
  }

  if (which == 2) {
#pragma unroll
    for (int half = 0; half < 2; ++half) {
      __syncthreads();
      if (wn == half) {
#pragma unroll
        for (int i = 0; i < 4; i++)
#pragma unroll
          for (int j = 0; j < 4; j++)
#pragma unroll
            for (int r = 0; r < 4; r++) {
              int nloc = j * 16 + c15;                  // 0..63
              int mloc = wm * 64 + i * 16 + g * 4 + r;  // 0..127
              float v = acc[i][j][r] + bv[n0 + half * 64 + nloc];
              T[nloc][mloc] = f2b(v);
            }
      }
      __syncthreads();
#pragma unroll
      for (int it = 0; it < 4; ++it) {
        int idx = it * 256 + tid;
        int row = idx >> 4;         // 0..63
        int cm = (idx & 15) * 8;    // 0..120
        int col = n0 + half * 64 + row;
        int hh = col >> 6, dd = col & 63;
        int m = m0 + cm;
        int bb2 = m >> 11, s = m & 2047;
        *(uint4*)&vt[(((bb2 * 16 + hh) * 64) + dd) * 2048 + s] =
            *(const uint4*)&T[row][cm];
      }
    }
    return;
  }

  const float* bias = (which == 0) ? bq : bk;
#pragma unroll
  for (int i = 0; i < 4; i++)
#pragma unroll
    for (int j = 0; j < 4; j++)
#pragma unroll
      for (int r = 0; r < 4; r++) {
        int row = m0 + wm * 64 + i * 16 + g * 4 + r;  // token 0..4095
        int col = n0 + wn * 64 + j * 16 + c15;        // 0..1023
        float v = acc[i][j][r] + bias[col];
        int bb = row >> 11, s = row & 2047;
        int hh = col >> 6, d = col & 63;
        if (which == 0) {
          Qcat[(((bb * 16 + hh) * 2048) + s) * 128 + d] =
              f2b(v * (0.0625f * LOG2E));
        } else {
          Kcat[(((bb * 16 + hh) * 2048) + s) * 128 + d] = f2b(v);
        }
      }
}

// ------------------------------------------------------------- helical -----
// Q-side outputs carry an extra log2e (K-side plain), matching qkv fold.
__global__ __launch_bounds__(256, 2) void helical_kernel(
    u16* __restrict__ Qcat, u16* __restrict__ Kcat,
    const u16* __restrict__ whb, const float* __restrict__ bhel) {
  __shared__ u16 A[2][2][64][32];  // [q/k][kq][row][32]
  __shared__ u16 Wl[2][64][32];    // Whel[h] bf16, [kq][e][32]
  const int sb = blockIdx.x, bh = blockIdx.y;
  const int h = bh & 15;
  const int s0 = sb << 6;
  const int tid = threadIdx.x;
  const int wave = tid >> 6, lane = tid & 63;
  const int g = lane >> 4, c15 = lane & 15;
  u16* Qb = Qcat + (long long)bh * (2048 * 128);
  u16* Kb = Kcat + (long long)bh * (2048 * 128);

#pragma unroll
  for (int it = 0; it < 2; ++it) {  // stage Whel[h]
    int cidx = it * 256 + tid;
    int e = cidx >> 3, ds = (cidx & 7) << 3;
    uint4 vv = *(const uint4*)(whb + h * 4096 + e * 64 + ds);
    *(uint4*)&Wl[ds >> 5][e][ds & 31] = vv;
  }
#pragma unroll
  for (int it = 0; it < 4; ++it) {  // stage q (undo fold) and k rows
    int cidx = it * 256 + tid;
    int which = cidx >> 9;
    int r = (cidx >> 3) & 63;
    int ds = (cidx & 7) << 3;
    const u16* src = (which ? Kb : Qb) + (s0 + r) * 128 + ds;
    uint4 vv = *(const uint4*)src;
    if (which == 0) {
      u16 tmp[8];
      *(uint4*)tmp = vv;
#pragma unroll
      for (int q = 0; q < 8; ++q)
        tmp[q] = f2b(b2f(tmp[q]) * (16.0f / LOG2E));
      vv = *(uint4*)tmp;
    }
    *(uint4*)&A[which][ds >> 5][r][ds & 31] = vv;
  }
  __syncthreads();

  const int which = wave >> 1, hf = wave & 1;
  f32x4 acc[2][4];
#pragma unroll
  for (int i = 0; i < 2; i++)
#pragma unroll
    for (int j = 0; j < 4; j++) acc[i][j] = f32x4{0.f, 0.f, 0.f, 0.f};
#pragma unroll
  for (int kq = 0; kq < 2; ++kq) {
    bf16x8 a0 = *(const bf16x8*)&A[which][kq][hf * 32 + c15][g * 8];
    bf16x8 a1 = *(const bf16x8*)&A[which][kq][hf * 32 + 16 + c15][g * 8];
#pragma unroll
    for (int j = 0; j < 4; ++j) {
      bf16x8 bb = *(const bf16x8*)&Wl[kq][j * 16 + c15][g * 8];
      acc[0][j] = mfma16(a0, bb, acc[0][j]);
      acc[1][j] = mfma16(a1, bb, acc[1][j]);
    }
  }
  u16* Dst = which ? Kb : Qb;
  const float oscale = which ? 0.125f : (0.125f * LOG2E);
#pragma unroll
  for (int i = 0; i < 2; ++i)
#pragma unroll
    for (int j = 0; j < 4; ++j)
#pragma unroll
      for (int r = 0; r < 4; ++r) {
        int s_loc = hf * 32 + i * 16 + g * 4 + r;
        int e = j * 16 + c15;
        float v = acc[i][j][r] + bhel[h * 64 + e];
        float pp = __shfl_xor(v, 1);  // pair partner (e^1), same row
        float nn = sqrtf(v * v + pp * pp);
        float o = v / fmaxf(nn, 1e-12f) * oscale;
        int s = s0 + s_loc;
        int u = s >> 1, c2 = s & 1;
        int row_out = ((e & 1) ? 1024 : 0) + u;
        int col_out = 64 + (e & ~1) + c2;
        Dst[row_out * 128 + col_out] = f2b(o);
      }
}

// ----------------------------------------------------------- attention -----
// Per (bh, 128-q tile), 8 waves: wq=w&3 (q quadrant), wt=w>>2 (t half).
// Pipelined single-barrier K-loop over 32 tiles of 64 t:
//   barrier (tile t DMA done) -> prefetch tile t+1 into other buffer ->
//   S^T = K·Q^T (8 mfma32, Q regs as B) -> exp2 -> P relayout in regs via
//   shfl_xor(32) -> O_partial += P·V over OWN t-half (4 mfma32).
// Cross-wt O partial sum + den at the end via LDS (Kl reused as scratch).
// LDS = 2*16 + 2*8 + 1 = 49 KB -> 2 blocks/CU; grid 512 = 2/CU exactly.
__global__ __launch_bounds__(512, 4) void attn_kernel(
    const u16* __restrict__ Qcat, const u16* __restrict__ Kcat,
    const u16* __restrict__ vt, u16* __restrict__ AO) {
  __shared__ u16 Kl[2][64][128];   // [buf][t-row][cat 16 chunks, swizzled]
  __shared__ u16 Vl[2][64][64];    // [buf][d-row][t 8 chunks, swizzled]
  __shared__ float denl[2][128];   // [wt][q-local]
  const int qt = blockIdx.x, bh = blockIdx.y;
  const int bb = bh >> 4, h = bh & 15;
  const int q0 = qt << 7;
  const int tid = threadIdx.x;
  const int w = tid >> 6, lane = tid & 63;
  const int wq = w & 3, wt = w >> 2;
  const int l31 = lane & 31, l5 = lane >> 5;
  const u16* Qb = Qcat + (long long)bh * (2048 * 128);
  const u16* Kb = Kcat + (long long)bh * (2048 * 128);
  const u16* Vb = vt + (long long)bh * (64 * 2048);

  // Q B-frags: n=l31 -> q = q0+32wq+l31; k = ks*16 + l5*8 + j
  bf16x8 qf[8];
  {
    const u16* qrow = Qb + (q0 + 32 * wq + l31) * 128 + l5 * 8;
#pragma unroll
    for (int ks = 0; ks < 8; ++ks) qf[ks] = *(const bf16x8*)(qrow + ks * 16);
  }

  // staging address precompute (XOR-swizzled 16B chunks)
  const int ll = tid;                 // 0..511
  const int krow0 = ll >> 4;          // pass 0: rows 0..31
  const int kp = ll & 15;
  const int ksrc0 = (kp & 8) | ((kp & 7) ^ (krow0 & 7));
  const int krow1 = 32 + krow0;       // pass 1: rows 32..63
  const int ksrc1 = (kp & 8) | ((kp & 7) ^ (krow1 & 7));
  const int vd = ll >> 3;
  const int vsrc = (ll & 7) ^ (vd & 7);

  // prologue: stage tile 0 into buf 0
  gld16(((u16*)Kl[0]) + ll * 8,        Kb + krow0 * 128 + ksrc0 * 8);
  gld16(((u16*)Kl[0]) + 4096 + ll * 8, Kb + krow1 * 128 + ksrc1 * 8);
  gld16(((u16*)Vl[0]) + ll * 8,        Vb + vd * 2048 + vsrc * 8);

  f32x16 accO0, accO1;
#pragma unroll
  for (int i = 0; i < 16; ++i) { accO0[i] = 0.f; accO1[i] = 0.f; }
  float den = 0.f;

  const int krow = 32 * wt + l31;  // S-phase A row (t-local)
  const int kr7 = krow & 7;

  for (int t = 0; t < 32; ++t) {
    const int cur = t & 1;
    __syncthreads();  // DMA(tile t) complete; readers of buf cur^1 done
    if (t + 1 < 32) {
      const int t1 = (t + 1) << 6;
      u16* Kd = (u16*)Kl[cur ^ 1];
      gld16(Kd + ll * 8,        Kb + (t1 + krow0) * 128 + ksrc0 * 8);
      gld16(Kd + 4096 + ll * 8, Kb + (t1 + krow1) * 128 + ksrc1 * 8);
      gld16(((u16*)Vl[cur ^ 1]) + ll * 8, Vb + vd * 2048 + t1 + vsrc * 8);
    }

    // ---- S^T[t-local 32wt..][q 32wq..] : 8 k-steps of 16 over cat=128
    f32x16 accS;
#pragma unroll
    for (int i = 0; i < 16; ++i) accS[i] = 0.f;
#pragma unroll
    for (int ks = 0; ks < 8; ++ks) {
      int lc = 2 * ks + l5;
      int p = (lc & 8) | ((lc & 7) ^ kr7);
      bf16x8 ak = *(const bf16x8*)&Kl[cur][krow][p * 8];
      accS = mfma32(ak, qf[ks], accS);
    }

    // ---- exp2 -> packed bf16 P (regs); per-lane den partial
    // C layout: lane holds q=32wq+l31 fixed; t-local = (reg&3)+8*(reg>>2)+4*l5
    u32 D0[2], D1[2], D2[2], D3[2];
#pragma unroll
    for (int rr = 0; rr < 4; ++rr) {
      float p0 = __builtin_amdgcn_exp2f(accS[4 * rr + 0]);
      float p1 = __builtin_amdgcn_exp2f(accS[4 * rr + 1]);
      float p2 = __builtin_amdgcn_exp2f(accS[4 * rr + 2]);
      float p3 = __builtin_amdgcn_exp2f(accS[4 * rr + 3]);
      den += (p0 + p1) + (p2 + p3);
      u32 lo = (__float_as_uint(p0) >> 16) | (__float_as_uint(p1) & 0xffff0000u);
      u32 hi = (__float_as_uint(p2) >> 16) | (__float_as_uint(p3) & 0xffff0000u);
      if (rr == 0) { D0[0] = lo; D0[1] = hi; }
      else if (rr == 1) { D1[0] = lo; D1[1] = hi; }
      else if (rr == 2) { D2[0] = lo; D2[1] = hi; }
      else { D3[0] = lo; D3[1] = hi; }
    }
    // cross-l5 exchange: build A-frags (m=q, k=t-local within own half)
    BFrag A0, A1;
    {
      u32 e00 = __shfl_xor((int)D0[0], 32), e01 = __shfl_xor((int)D0[1], 32);
      u32 e10 = __shfl_xor((int)D1[0], 32), e11 = __shfl_xor((int)D1[1], 32);
      u32 e20 = __shfl_xor((int)D2[0], 32), e21 = __shfl_xor((int)D2[1], 32);
      u32 e30 = __shfl_xor((int)D3[0], 32), e31 = __shfl_xor((int)D3[1], 32);
      A0.u[0] = l5 ? e10 : D0[0];
      A0.u[1] = l5 ? e11 : D0[1];
      A0.u[2] = l5 ? D1[0] : e00;
      A0.u[3] = l5 ? D1[1] : e01;
      A1.u[0] = l5 ? e30 : D2[0];
      A1.u[1] = l5 ? e31 : D2[1];
      A1.u[2] = l5 ? D3[0] : e20;
      A1.u[3] = l5 ? D3[1] : e21;
    }

    // ---- O_partial[q 32wq..][d 0..63] += P · V over OWN t-half (k=32)
#pragma unroll
    for (int dq = 0; dq < 2; ++dq) {
      int d = 32 * dq + l31;
      int d7 = d & 7;
#pragma unroll
      for (int ks = 0; ks < 2; ++ks) {
        int lc = 4 * wt + 2 * ks + l5;
        bf16x8 bvf = *(const bf16x8*)&Vl[cur][d][((lc ^ d7) & 7) * 8];
        if (dq == 0) accO0 = mfma32(ks ? A1.b : A0.b, bvf, accO0);
        else         accO1 = mfma32(ks ? A1.b : A0.b, bvf, accO1);
      }
    }
  }

  // ---- den: lane partial covers 16 of own t-half's 32; partner has rest
  den += __shfl_xor(den, 32);
  if (lane < 32) denl[wt][32 * wq + lane] = den;
  __syncthreads();

  // ---- cross-wt O partial reduction via LDS scratch (reuse Kl: 8192 f32)
  float* S = (float*)Kl;
  if (wt == 1) {
#pragma unroll
    for (int r = 0; r < 16; ++r) {
      int qr = (r & 3) + 8 * (r >> 2) + 4 * l5;  // 0..31
      S[(wq * 32 + qr) * 64 + l31] = accO0[r];
      S[(wq * 32 + qr) * 64 + 32 + l31] = accO1[r];
    }
  }
  __syncthreads();
  if (wt == 0) {
#pragma unroll
    for (int r = 0; r < 16; ++r) {
      int qr = (r & 3) + 8 * (r >> 2) + 4 * l5;
      int ql = 32 * wq + qr;
      float inv = 1.0f / (denl[0][ql] + denl[1][ql]);
      float o0 = (accO0[r] + S[(wq * 32 + qr) * 64 + l31]) * inv;
      float o1 = (accO1[r] + S[(wq * 32 + qr) * 64 + 32 + l31]) * inv;
      long long base = ((long long)(bb * 2048 + q0 + ql) * 1024) + h * 64;
      AO[base + l31] = f2b(o0);
      AO[base + 32 + l31] = f2b(o1);
    }
  }
}

// ----------------------------------------------------------- out GEMM -----
// Double-buffered prefetch-after-barrier pipeline (1 barrier/K-step).
__global__ __launch_bounds__(256, 2) void out_gemm(
    const u16* __restrict__ AO, const u16* __restrict__ wob,
    const float* __restrict__ bo, float* __restrict__ out) {
  __shared__ u16 Al[2][128][32];
  __shared__ u16 Bl[2][128][32];
  const int n0 = blockIdx.x << 7;
  const int m0 = blockIdx.y << 7;
  const int tid = threadIdx.x;
  const int wave = tid >> 6, lane = tid & 63;
  const int g = lane >> 4, c15 = lane & 15;
  const int wm = wave & 1, wn = wave >> 1;
  const u16* Wp = wob + n0 * 1024;
  const u16* Ap = AO + m0 * 1024;
  const int srow = (wave * 64 + lane) >> 2;
  const int scol = (lane & 3) << 3;

  f32x4 acc[4][4];
#pragma unroll
  for (int i = 0; i < 4; i++)
#pragma unroll
    for (int j = 0; j < 4; j++) acc[i][j] = f32x4{0.f, 0.f, 0.f, 0.f};

  gld16(&Al[0][srow][scol],      Ap + srow * 1024 + scol);
  gld16(&Al[0][64 + srow][scol], Ap + (64 + srow) * 1024 + scol);
  gld16(&Bl[0][srow][scol],      Wp + srow * 1024 + scol);
  gld16(&Bl[0][64 + srow][scol], Wp + (64 + srow) * 1024 + scol);

  for (int k0 = 0; k0 < 1024; k0 += 32) {
    const int c = (k0 >> 5) & 1;
    __syncthreads();
    if (k0 + 32 < 1024) {
      const int kn = k0 + 32;
      gld16(&Al[c ^ 1][srow][scol],      Ap + srow * 1024 + kn + scol);
      gld16(&Al[c ^ 1][64 + srow][scol], Ap + (64 + srow) * 1024 + kn + scol);
      gld16(&Bl[c ^ 1][srow][scol],      Wp + srow * 1024 + kn + scol);
      gld16(&Bl[c ^ 1][64 + srow][scol], Wp + (64 + srow) * 1024 + kn + scol);
    }
    bf16x8 a[4], b[4];
#pragma unroll
    for (int i = 0; i < 4; i++)
      a[i] = *(const bf16x8*)&Al[c][wm * 64 + i * 16 + c15][g * 8];
#pragma unroll
    for (int j = 0; j < 4; j++)
      b[j] = *(const bf16x8*)&Bl[c][wn * 64 + j * 16 + c15][g * 8];
#pragma unroll
    for (int i = 0; i < 4; i++)
#pragma unroll
      for (int j = 0; j < 4; j++) acc[i][j] = mfma16(a[i], b[j], acc[i][j]);
  }
#pragma unroll
  for (int i = 0; i < 4; i++)
#pragma unroll
    for (int j = 0; j < 4; j++)
#pragma unroll
      for (int r = 0; r < 4; r++) {
        int row = m0 + wm * 64 + i * 16 + g * 4 + r;
        int col = n0 + wn * 64 + j * 16 + c15;
        out[row * 1024 + col] = acc[i][j][r] + bo[col];
      }
}

// -------------------------------------------------------------- launch -----
extern "C" void kernel_launch(void* const* d_in, const int* in_sizes, int n_in,
                              void* d_out, int out_size, void* d_ws,
                              size_t ws_size, hipStream_t stream) {
  const float* x    = (const float*)d_in[0];
  const float* Wq   = (const float*)d_in[1];
  const float* bq   = (const float*)d_in[2];
  const float* Wk   = (const float*)d_in[3];
  const float* bk   = (const float*)d_in[4];
  const float* Wv   = (const float*)d_in[5];
  const float* bv   = (const float*)d_in[6];
  const float* Wo   = (const float*)d_in[7];
  const float* bo   = (const float*)d_in[8];
  const float* Whel = (const float*)d_in[9];
  const float* bhel = (const float*)d_in[10];
  float* out = (float*)d_out;

  char* ws = (char*)d_ws;
  u16* xb   = (u16*)(ws + 0);                  //  8 MB
  u16* wb   = (u16*)(ws + 8388608);            //  6 MB (Wq|Wk|Wv)
  u16* wob  = (u16*)(ws + 14680064);           //  2 MB
  u16* whb  = (u16*)(ws + 16777216);           //  128 KB
  u16* Qcat = (u16*)(ws + 16908288);           // 16 MB  [bh][s][128]
  u16* Kcat = (u16*)(ws + 33685504);           // 16 MB
  u16* vt   = (u16*)(ws + 50462720);           //  8 MB  [bh][d][t]
  u16* AO   = (u16*)(ws + 58851328);           //  8 MB  (total ~64.1 MB)

  cast_kernel<<<dim3(8256), dim3(256), 0, stream>>>(x, Wq, Wk, Wv, Wo, Whel,
                                                    xb, wb, wob, whb);
  qkv_gemm<<<dim3(24, 32), dim3(256), 0, stream>>>(xb, wb, bq, bk, bv, Qcat,
                                                   Kcat, vt);
  helical_kernel<<<dim3(32, 32), dim3(256), 0, stream>>>(Qcat, Kcat, whb,
                                                         bhel);
  attn_kernel<<<dim3(16, 32), dim3(512), 0, stream>>>(Qcat, Kcat, vt, AO);
  out_gemm<<<dim3(8, 32), dim3(256), 0, stream>>>(AO, wob, bo, out);
}